// Round 1
// baseline (584.506 us; speedup 1.0000x reference)
//
#include <hip/hip_runtime.h>
#include <math.h>

constexpr int B = 8, S = 1024, D = 256, H = 8, HD = 32;

// ---------------------------------------------------------------------------
// K1: projection GEMM  y[m,n] = sum_k x[m,k]*W[n,k] + bias[n]
//     M = B*S = 8192, N = K = 256.  Tiles 64x64, BK=16, 256 threads, 4x4 micro.
// ---------------------------------------------------------------------------
__global__ __launch_bounds__(256) void proj_gemm(
    const float* __restrict__ x, const float* __restrict__ W,
    const float* __restrict__ bias, float* __restrict__ y)
{
    constexpr int K = D, N = D;
    __shared__ float xs[16][64];   // [kk][m] transposed for b128 fragment reads
    __shared__ float ws[16][64];   // [kk][n]
    const int m0 = blockIdx.x * 64;
    const int n0 = blockIdx.y * 64;
    const int tid = threadIdx.x;
    const int tm = tid >> 4, tn = tid & 15;
    const int lrow = tid >> 2;
    const int lcol = (tid & 3) * 4;
    float acc[4][4] = {};
    for (int k0 = 0; k0 < K; k0 += 16) {
        float4 xv = *(const float4*)&x[(size_t)(m0 + lrow) * K + k0 + lcol];
        float4 wv = *(const float4*)&W[(size_t)(n0 + lrow) * K + k0 + lcol];
        xs[lcol + 0][lrow] = xv.x; xs[lcol + 1][lrow] = xv.y;
        xs[lcol + 2][lrow] = xv.z; xs[lcol + 3][lrow] = xv.w;
        ws[lcol + 0][lrow] = wv.x; ws[lcol + 1][lrow] = wv.y;
        ws[lcol + 2][lrow] = wv.z; ws[lcol + 3][lrow] = wv.w;
        __syncthreads();
        #pragma unroll
        for (int kk = 0; kk < 16; ++kk) {
            float a[4], bv[4];
            *(float4*)a  = *(const float4*)&xs[kk][tm * 4];
            *(float4*)bv = *(const float4*)&ws[kk][tn * 4];
            #pragma unroll
            for (int i = 0; i < 4; ++i)
                #pragma unroll
                for (int j = 0; j < 4; ++j)
                    acc[i][j] += a[i] * bv[j];
        }
        __syncthreads();
    }
    #pragma unroll
    for (int i = 0; i < 4; ++i) {
        int m = m0 + tm * 4 + i;
        int n = n0 + tn * 4;
        float4 r;
        r.x = acc[i][0] + bias[n + 0];
        r.y = acc[i][1] + bias[n + 1];
        r.z = acc[i][2] + bias[n + 2];
        r.w = acc[i][3] + bias[n + 3];
        *(float4*)&y[(size_t)m * N + n] = r;
    }
}

// ---------------------------------------------------------------------------
// K2: time-decay + relation attention (head-independent weights), writes out:
//   out[b,i,:] = c_t * sum_{j<=i} Tw(i,j) v[b,j,:]  +  rel part (j>i, or uniform)
// Tw = softmax_j(exp(-|ts|)) without max-sub (values in (0,1]); rel likewise.
// Block: (b, 32-row tile), 256 threads.
// ---------------------------------------------------------------------------
__global__ __launch_bounds__(256) void timerel_kernel(
    const float* __restrict__ ts, const float* __restrict__ rel,
    const float* __restrict__ v, const float* __restrict__ l1p,
    const float* __restrict__ l2p, float* __restrict__ out)
{
    __shared__ float w2[32][64];           // [r][j] weight tile
    __shared__ float tsc[32], rsc[32], runi[32];
    const int b  = blockIdx.y;
    const int i0 = blockIdx.x * 32;
    const int tid = threadIdx.x;

    // ---- phase A: per-row normalizers (8 threads per row) ----
    {
        const int r = tid >> 3, slot = tid & 7;
        const int i = i0 + r;
        const float* tsrow  = ts  + ((size_t)b * S + i) * S;
        const float* relrow = rel + ((size_t)b * S + i) * S;
        float st = 0.f, sr = 0.f;
        for (int j = slot; j < S; j += 8) {
            if (j <= i) {
                st += __expf(__expf(-fabsf(tsrow[j])));
            } else {
                float rv = relrow[j];
                if (rv != 0.f) sr += __expf(rv);   // rel==0 in future -> masked (-10000)
            }
        }
        st += __shfl_xor(st, 1); st += __shfl_xor(st, 2); st += __shfl_xor(st, 4);
        sr += __shfl_xor(sr, 1); sr += __shfl_xor(sr, 2); sr += __shfl_xor(sr, 4);
        if (slot == 0) {
            const float l1 = l1p[0], l2 = l2p[0];
            tsc[r]  = (1.f - l1) * l2 / st;
            rsc[r]  = (sr > 0.f) ? (l1 / sr) : 0.f;
            runi[r] = (sr > 0.f) ? 0.f : (l1 / (float)S);  // all-masked row: uniform 1/S
        }
    }
    __syncthreads();

    // ---- phase B: O[32 x 256] += W2[32 x S] @ V[S x 256], j-tiles of 64 ----
    // thread = rg*64 + dg : owns rows rg*8..rg*8+7, cols dg*4..dg*4+3.
    // Per wave all lanes share rg -> w2 reads are pure LDS broadcasts.
    const int rg = tid >> 6, dg = tid & 63;
    float o[8][4] = {};
    for (int jt = 0; jt < S; jt += 64) {
        const int j = jt + dg;
        #pragma unroll
        for (int rr = 0; rr < 8; ++rr) {
            const int r = rg * 8 + rr;
            const int i = i0 + r;
            float w = runi[r];
            if (j <= i) {
                w += __expf(__expf(-fabsf(ts[((size_t)b * S + i) * S + j]))) * tsc[r];
            } else {
                float rv = rel[((size_t)b * S + i) * S + j];
                if (rv != 0.f) w += __expf(rv) * rsc[r];
            }
            w2[r][dg] = w;
        }
        __syncthreads();
        const float* vbase = v + ((size_t)b * S + jt) * D + dg * 4;
        #pragma unroll 4
        for (int jj = 0; jj < 64; ++jj) {
            float4 vv = *(const float4*)(vbase + (size_t)jj * D);
            #pragma unroll
            for (int rr = 0; rr < 8; ++rr) {
                float wv = w2[rg * 8 + rr][jj];
                o[rr][0] += wv * vv.x;
                o[rr][1] += wv * vv.y;
                o[rr][2] += wv * vv.z;
                o[rr][3] += wv * vv.w;
            }
        }
        __syncthreads();
    }
    #pragma unroll
    for (int rr = 0; rr < 8; ++rr) {
        const int i = i0 + rg * 8 + rr;
        float4 r4;
        r4.x = o[rr][0]; r4.y = o[rr][1]; r4.z = o[rr][2]; r4.w = o[rr][3];
        *(float4*)&out[((size_t)b * S + i) * D + dg * 4] = r4;
    }
}

// ---------------------------------------------------------------------------
// K3: causal dot-product flash attention, out += c_p * softmax(qk^T/sqrt(hd)) v
// Block: (b, h, 8 rows). 4 waves, 2 rows per wave, one j per lane per tile.
// K/V tiles in LDS, stride 34 floats (b64 reads -> 2-way conflicts = free).
// ---------------------------------------------------------------------------
__device__ __forceinline__ void row_reduce_store(
    float* __restrict__ op, const float (&o)[32], float m, float l,
    float c_p, int lane)
{
    float M = m;
    #pragma unroll
    for (int off = 32; off > 0; off >>= 1)
        M = fmaxf(M, __shfl_xor(M, off));
    float cs = __expf(m - M);          // lanes with no work: m=-3e38 -> cs=0
    float ls = l * cs;
    #pragma unroll
    for (int off = 32; off > 0; off >>= 1)
        ls += __shfl_xor(ls, off);
    float res = 0.f;
    #pragma unroll
    for (int d = 0; d < 32; ++d) {
        float t = o[d] * cs;
        #pragma unroll
        for (int off = 32; off > 0; off >>= 1)
            t += __shfl_xor(t, off);
        if (lane == d) res = t;        // static index select, no scratch
    }
    if (lane < 32) op[lane] += c_p * res / ls;
}

__global__ __launch_bounds__(256) void flash_kernel(
    const float* __restrict__ qg, const float* __restrict__ kg,
    const float* __restrict__ vg, const float* __restrict__ l1p,
    const float* __restrict__ l2p, float* __restrict__ out)
{
    __shared__ float ks[64][34];
    __shared__ float vs[64][34];
    const int b = blockIdx.z, h = blockIdx.y;
    const int i0 = blockIdx.x * 8;
    const int wv = threadIdx.x >> 6, lane = threadIdx.x & 63;
    const int ia = i0 + wv * 2, ib = ia + 1;
    const float c_p = (1.f - l1p[0]) * (1.f - l2p[0]);
    const float scale = 0.17677669529663687f;   // 1/sqrt(32), folded into q
    float qa[32], qb[32];
    {
        const float* qra = qg + ((size_t)b * S + ia) * D + h * HD;
        #pragma unroll
        for (int d = 0; d < 32; ++d) {
            qa[d] = qra[d] * scale;
            qb[d] = qra[D + d] * scale;
        }
    }
    float ma = -3.0e38f, la = 0.f, mbv = -3.0e38f, lb = 0.f;
    float oa[32] = {}, ob[32] = {};
    const int lastj = i0 + 7;
    const int lr = threadIdx.x >> 2;
    const int lc = (threadIdx.x & 3) * 8;
    for (int jt = 0; jt <= lastj; jt += 64) {
        {   // cooperative K/V tile load: 64 rows x 32 cols each
            const float* kr = kg + ((size_t)b * S + jt + lr) * D + h * HD + lc;
            const float* vr = vg + ((size_t)b * S + jt + lr) * D + h * HD + lc;
            float4 k0 = *(const float4*)kr;
            float4 k1 = *(const float4*)(kr + 4);
            float4 v0 = *(const float4*)vr;
            float4 v1 = *(const float4*)(vr + 4);
            ks[lr][lc+0]=k0.x; ks[lr][lc+1]=k0.y; ks[lr][lc+2]=k0.z; ks[lr][lc+3]=k0.w;
            ks[lr][lc+4]=k1.x; ks[lr][lc+5]=k1.y; ks[lr][lc+6]=k1.z; ks[lr][lc+7]=k1.w;
            vs[lr][lc+0]=v0.x; vs[lr][lc+1]=v0.y; vs[lr][lc+2]=v0.z; vs[lr][lc+3]=v0.w;
            vs[lr][lc+4]=v1.x; vs[lr][lc+5]=v1.y; vs[lr][lc+6]=v1.z; vs[lr][lc+7]=v1.w;
        }
        __syncthreads();
        const int j = jt + lane;
        float sa = 0.f, sb = 0.f;
        #pragma unroll
        for (int d = 0; d < 32; d += 2) {
            float2 kk = *(const float2*)&ks[lane][d];
            sa += qa[d] * kk.x + qa[d + 1] * kk.y;
            sb += qb[d] * kk.x + qb[d + 1] * kk.y;
        }
        float pa = 0.f, ca = 1.f, pb = 0.f, cb = 1.f;
        const bool ua = (j <= ia), ub = (j <= ib);
        if (ua) {
            float mn = fmaxf(ma, sa);
            pa = __expf(sa - mn);
            ca = __expf(ma - mn);
            la = la * ca + pa;
            ma = mn;
        }
        if (ub) {
            float mn = fmaxf(mbv, sb);
            pb = __expf(sb - mn);
            cb = __expf(mbv - mn);
            lb = lb * cb + pb;
            mbv = mn;
        }
        if (ua || ub) {
            #pragma unroll
            for (int d = 0; d < 32; d += 2) {
                float2 vvv = *(const float2*)&vs[lane][d];
                oa[d]     = oa[d]     * ca + pa * vvv.x;
                oa[d + 1] = oa[d + 1] * ca + pa * vvv.y;
                ob[d]     = ob[d]     * cb + pb * vvv.x;
                ob[d + 1] = ob[d + 1] * cb + pb * vvv.y;
            }
        }
        __syncthreads();
    }
    float* opa = out + ((size_t)b * S + ia) * D + h * HD;
    row_reduce_store(opa,     oa, ma,  la, c_p, lane);
    row_reduce_store(opa + D, ob, mbv, lb, c_p, lane);
}

// ---------------------------------------------------------------------------
extern "C" void kernel_launch(void* const* d_in, const int* in_sizes, int n_in,
                              void* d_out, int out_size, void* d_ws, size_t ws_size,
                              hipStream_t stream)
{
    (void)in_sizes; (void)n_in; (void)out_size; (void)ws_size;
    const float* query = (const float*)d_in[0];
    const float* key_  = (const float*)d_in[1];
    const float* value = (const float*)d_in[2];
    const float* rel   = (const float*)d_in[3];
    const float* tsp   = (const float*)d_in[4];
    const float* l1p   = (const float*)d_in[5];
    const float* l2p   = (const float*)d_in[6];
    const float* Wq    = (const float*)d_in[7];
    const float* bq    = (const float*)d_in[8];
    const float* Wk    = (const float*)d_in[9];
    const float* bk    = (const float*)d_in[10];
    const float* Wv    = (const float*)d_in[11];
    const float* bv    = (const float*)d_in[12];
    float* out = (float*)d_out;

    // workspace: projected q, k, v as f32 [B,S,D]  (3 * 8 MiB = 24 MiB)
    float* qp = (float*)d_ws;
    float* kp = qp + (size_t)B * S * D;
    float* vp = kp + (size_t)B * S * D;

    dim3 gproj(B * S / 64, D / 64);
    proj_gemm<<<gproj, 256, 0, stream>>>(query, Wq, bq, qp);
    proj_gemm<<<gproj, 256, 0, stream>>>(key_,  Wk, bk, kp);
    proj_gemm<<<gproj, 256, 0, stream>>>(value, Wv, bv, vp);

    // writes full d_out (time + rel contributions, head-independent)
    timerel_kernel<<<dim3(S / 32, B), 256, 0, stream>>>(tsp, rel, vp, l1p, l2p, out);

    // adds causal dot-product attention contribution
    flash_kernel<<<dim3(S / 8, H, B), 256, 0, stream>>>(qp, kp, vp, l1p, l2p, out);
}

// Round 2
// 262.217 us; speedup vs baseline: 2.2291x; 2.2291x over previous
//
#include <hip/hip_runtime.h>
#include <math.h>

constexpr int B = 8, S = 1024, D = 256, H = 8, HD = 32;

typedef __attribute__((ext_vector_type(8))) short bf16x8;
typedef __attribute__((ext_vector_type(16))) float f32x16;

__device__ __forceinline__ ushort f2bf(float f) {
    uint u = __float_as_uint(f);
    return (ushort)((u + 0x7FFFu + ((u >> 16) & 1u)) >> 16);
}
__device__ __forceinline__ uint cvtpk(float a, float b) {
    uint r;
    asm("v_cvt_pk_bf16_f32 %0, %1, %2" : "=v"(r) : "v"(a), "v"(b));
    return r;
}

// ---------------------------------------------------------------------------
// K1: projection GEMM  y[m,n] = sum_k x[m,k]*W[n,k] + bias[n]
// MODE 0: write bf16 in QK-fragment layout only (scaled).
//         layout: [b][h][tile32 of s][c2][hi2][s31][j8]  (elem offset)
// MODE 1: write f32 y (for timerel) + bf16 V^T fragment layout:
//         layout: [b][h][tile32 of s][kc2][hi2][d32][j8], value V[s][d]
// ---------------------------------------------------------------------------
template<int MODE>
__global__ __launch_bounds__(256) void proj_gemm(
    const float* __restrict__ x, const float* __restrict__ W,
    const float* __restrict__ bias, float scale,
    float* __restrict__ yf, ushort* __restrict__ yb)
{
    constexpr int K = D;
    __shared__ float xs[16][64];
    __shared__ float ws[16][64];
    const int m0 = blockIdx.x * 64;
    const int n0 = blockIdx.y * 64;
    const int tid = threadIdx.x;
    const int tm = tid >> 4, tn = tid & 15;
    const int lrow = tid >> 2;
    const int lcol = (tid & 3) * 4;
    float acc[4][4] = {};
    for (int k0 = 0; k0 < K; k0 += 16) {
        float4 xv = *(const float4*)&x[(size_t)(m0 + lrow) * K + k0 + lcol];
        float4 wv = *(const float4*)&W[(size_t)(n0 + lrow) * K + k0 + lcol];
        xs[lcol + 0][lrow] = xv.x; xs[lcol + 1][lrow] = xv.y;
        xs[lcol + 2][lrow] = xv.z; xs[lcol + 3][lrow] = xv.w;
        ws[lcol + 0][lrow] = wv.x; ws[lcol + 1][lrow] = wv.y;
        ws[lcol + 2][lrow] = wv.z; ws[lcol + 3][lrow] = wv.w;
        __syncthreads();
        #pragma unroll
        for (int kk = 0; kk < 16; ++kk) {
            float a[4], bv[4];
            *(float4*)a  = *(const float4*)&xs[kk][tm * 4];
            *(float4*)bv = *(const float4*)&ws[kk][tn * 4];
            #pragma unroll
            for (int i = 0; i < 4; ++i)
                #pragma unroll
                for (int j = 0; j < 4; ++j)
                    acc[i][j] += a[i] * bv[j];
        }
        __syncthreads();
    }
    const int mbase = m0 + tm * 4;
    const int nbase = n0 + tn * 4;
    float vals[4][4];
    #pragma unroll
    for (int i = 0; i < 4; ++i)
        #pragma unroll
        for (int j = 0; j < 4; ++j)
            vals[i][j] = acc[i][j] + bias[nbase + j];

    const int b_ = mbase >> 10;          // S = 1024
    const int s  = mbase & 1023;         // multiple of 4
    const int h_ = nbase >> 5;

    if constexpr (MODE == 0) {
        // Q/K fragment layout: hd = c*16 + hig*8 + j
        const int hd = nbase & 31;       // multiple of 4 -> j0 in {0,4}
        const int c = hd >> 4, hig = (hd >> 3) & 1, j0 = hd & 7;
        size_t tb = ((((size_t)b_ * H + h_) * 32 + (s >> 5)) * 1024)
                    + c * 512 + hig * 256 + (size_t)(s & 31) * 8 + j0;
        #pragma unroll
        for (int i = 0; i < 4; ++i) {
            ushort4 pk = { f2bf(vals[i][0] * scale), f2bf(vals[i][1] * scale),
                           f2bf(vals[i][2] * scale), f2bf(vals[i][3] * scale) };
            *(ushort4*)&yb[tb + (size_t)i * 8] = pk;
        }
    } else {
        #pragma unroll
        for (int i = 0; i < 4; ++i) {
            float4 r4; r4.x = vals[i][0]; r4.y = vals[i][1];
                       r4.z = vals[i][2]; r4.w = vals[i][3];
            *(float4*)&yf[(size_t)(mbase + i) * D + nbase] = r4;
        }
        // V^T fragment layout: s = tile*32 + kc*16 + hig*8 + j
        const int d0 = nbase & 31;
        const int kc = (s >> 4) & 1, hig = (s >> 3) & 1, j0 = s & 7;
        size_t tb = ((((size_t)b_ * H + h_) * 32 + (s >> 5)) * 1024)
                    + kc * 512 + hig * 256 + j0;
        #pragma unroll
        for (int jj = 0; jj < 4; ++jj) {
            ushort4 pk = { f2bf(vals[0][jj]), f2bf(vals[1][jj]),
                           f2bf(vals[2][jj]), f2bf(vals[3][jj]) };
            *(ushort4*)&yb[tb + (size_t)(d0 + jj) * 8] = pk;
        }
    }
}

// ---------------------------------------------------------------------------
// K2: time-decay + relation attention (head-independent), writes full out
// ---------------------------------------------------------------------------
__global__ __launch_bounds__(256) void timerel_kernel(
    const float* __restrict__ ts, const float* __restrict__ rel,
    const float* __restrict__ v, const float* __restrict__ l1p,
    const float* __restrict__ l2p, float* __restrict__ out)
{
    __shared__ float w2[32][64];
    __shared__ float tsc[32], rsc[32], runi[32];
    const int b  = blockIdx.y;
    const int i0 = blockIdx.x * 32;
    const int tid = threadIdx.x;
    {
        const int r = tid >> 3, slot = tid & 7;
        const int i = i0 + r;
        const float* tsrow  = ts  + ((size_t)b * S + i) * S;
        const float* relrow = rel + ((size_t)b * S + i) * S;
        float st = 0.f, sr = 0.f;
        for (int j = slot; j < S; j += 8) {
            if (j <= i) {
                st += __expf(__expf(-fabsf(tsrow[j])));
            } else {
                float rv = relrow[j];
                if (rv != 0.f) sr += __expf(rv);
            }
        }
        st += __shfl_xor(st, 1); st += __shfl_xor(st, 2); st += __shfl_xor(st, 4);
        sr += __shfl_xor(sr, 1); sr += __shfl_xor(sr, 2); sr += __shfl_xor(sr, 4);
        if (slot == 0) {
            const float l1 = l1p[0], l2 = l2p[0];
            tsc[r]  = (1.f - l1) * l2 / st;
            rsc[r]  = (sr > 0.f) ? (l1 / sr) : 0.f;
            runi[r] = (sr > 0.f) ? 0.f : (l1 / (float)S);
        }
    }
    __syncthreads();
    const int rg = tid >> 6, dg = tid & 63;
    float o[8][4] = {};
    for (int jt = 0; jt < S; jt += 64) {
        const int j = jt + dg;
        #pragma unroll
        for (int rr = 0; rr < 8; ++rr) {
            const int r = rg * 8 + rr;
            const int i = i0 + r;
            float w = runi[r];
            if (j <= i) {
                w += __expf(__expf(-fabsf(ts[((size_t)b * S + i) * S + j]))) * tsc[r];
            } else {
                float rv = rel[((size_t)b * S + i) * S + j];
                if (rv != 0.f) w += __expf(rv) * rsc[r];
            }
            w2[r][dg] = w;
        }
        __syncthreads();
        const float* vbase = v + ((size_t)b * S + jt) * D + dg * 4;
        #pragma unroll 4
        for (int jj = 0; jj < 64; ++jj) {
            float4 vv = *(const float4*)(vbase + (size_t)jj * D);
            #pragma unroll
            for (int rr = 0; rr < 8; ++rr) {
                float wv = w2[rg * 8 + rr][jj];
                o[rr][0] += wv * vv.x;
                o[rr][1] += wv * vv.y;
                o[rr][2] += wv * vv.z;
                o[rr][3] += wv * vv.w;
            }
        }
        __syncthreads();
    }
    #pragma unroll
    for (int rr = 0; rr < 8; ++rr) {
        const int i = i0 + rg * 8 + rr;
        float4 r4;
        r4.x = o[rr][0]; r4.y = o[rr][1]; r4.z = o[rr][2]; r4.w = o[rr][3];
        *(float4*)&out[((size_t)b * S + i) * D + dg * 4] = r4;
    }
}

// ---------------------------------------------------------------------------
// K3: MFMA flash attention (swapped operands), out += c_p * softmax(QK^T)V
// Wave owns 32 q-rows. S^T = mfma(K,Q); OT = mfma(V^T,P). No LDS in main loop.
// ---------------------------------------------------------------------------
#define LOADKV(K0, K1, V0, V1, KT) do { \
    const ushort* kp_ = kbase + (size_t)(KT) * 1024; \
    const ushort* vp_ = vbase + (size_t)(KT) * 1024; \
    K0 = *(const bf16x8*)kp_;        K1 = *(const bf16x8*)(kp_ + 512); \
    V0 = *(const bf16x8*)vp_;        V1 = *(const bf16x8*)(vp_ + 512); \
} while (0)

#define TILE_COMPUTE(K0, K1, V0, V1, ISDIAG) do { \
    f32x16 st; \
    _Pragma("unroll") for (int r = 0; r < 16; ++r) st[r] = 0.f; \
    st = __builtin_amdgcn_mfma_f32_32x32x16_bf16(K0, qf0, st, 0, 0, 0); \
    st = __builtin_amdgcn_mfma_f32_32x32x16_bf16(K1, qf1, st, 0, 0, 0); \
    if (ISDIAG) { \
        _Pragma("unroll") for (int r = 0; r < 16; ++r) \
            if (((r & 3) + 8 * (r >> 2) + 4 * hi) > l31) st[r] = -1e30f; \
    } \
    float pmax = st[0]; \
    _Pragma("unroll") for (int r = 1; r < 16; ++r) pmax = fmaxf(pmax, st[r]); \
    pmax = fmaxf(pmax, __shfl_xor(pmax, 32)); \
    const float mnew = fmaxf(mrun, pmax); \
    const float csc = exp2f(mrun - mnew); \
    float p[16]; float psum = 0.f; \
    _Pragma("unroll") for (int r = 0; r < 16; ++r) { p[r] = exp2f(st[r] - mnew); psum += p[r]; } \
    psum += __shfl_xor(psum, 32); \
    lrun = lrun * csc + psum; mrun = mnew; \
    _Pragma("unroll") for (int r = 0; r < 16; ++r) ot[r] *= csc; \
    uint wa0 = cvtpk(p[0], p[1]),   wa1 = cvtpk(p[2], p[3]); \
    uint wb0 = cvtpk(p[4], p[5]),   wb1 = cvtpk(p[6], p[7]); \
    uint wa2 = cvtpk(p[8], p[9]),   wa3 = cvtpk(p[10], p[11]); \
    uint wb2 = cvtpk(p[12], p[13]), wb3 = cvtpk(p[14], p[15]); \
    uint t0 = (uint)__shfl_xor((int)wb0, 32), u0 = (uint)__shfl_xor((int)wa0, 32); \
    uint t1 = (uint)__shfl_xor((int)wb1, 32), u1 = (uint)__shfl_xor((int)wa1, 32); \
    uint t2 = (uint)__shfl_xor((int)wb2, 32), u2 = (uint)__shfl_xor((int)wa2, 32); \
    uint t3 = (uint)__shfl_xor((int)wb3, 32), u3 = (uint)__shfl_xor((int)wa3, 32); \
    uint4 pa0i = { hi ? t0 : wa0, hi ? t1 : wa1, hi ? wb0 : u0, hi ? wb1 : u1 }; \
    uint4 pa1i = { hi ? t2 : wa2, hi ? t3 : wa3, hi ? wb2 : u2, hi ? wb3 : u3 }; \
    bf16x8 pa0 = __builtin_bit_cast(bf16x8, pa0i); \
    bf16x8 pa1 = __builtin_bit_cast(bf16x8, pa1i); \
    ot = __builtin_amdgcn_mfma_f32_32x32x16_bf16(V0, pa0, ot, 0, 0, 0); \
    ot = __builtin_amdgcn_mfma_f32_32x32x16_bf16(V1, pa1, ot, 0, 0, 0); \
} while (0)

__global__ __launch_bounds__(256) void flash_mfma(
    const ushort* __restrict__ qb, const ushort* __restrict__ kb,
    const ushort* __restrict__ vtb, const float* __restrict__ l1p,
    const float* __restrict__ l2p, float* __restrict__ out)
{
    __shared__ float lds_t[4][32 * 33];
    const int id = blockIdx.x;
    const int halfg = id >> 8, rr_ = id & 255;
    const int qraw = rr_ >> 5;
    const int qblk = halfg ? (7 - qraw) : qraw;     // complement-paired balance
    const int bh = (rr_ & 31) | (halfg << 5);
    const int b = bh >> 3, h = bh & 7;
    const int w = threadIdx.x >> 6, lane = threadIdx.x & 63;
    const int l31 = lane & 31, hi = lane >> 5;
    const int qt = qblk * 4 + w;                    // wave's 32-row q tile
    const float c_p = (1.f - l1p[0]) * (1.f - l2p[0]);

    const ushort* qp_ = qb + ((size_t)bh * 32 + qt) * 1024 + hi * 256 + l31 * 8;
    const bf16x8 qf0 = *(const bf16x8*)qp_;
    const bf16x8 qf1 = *(const bf16x8*)(qp_ + 512);
    const ushort* kbase = kb  + (size_t)bh * 32768 + hi * 256 + l31 * 8;
    const ushort* vbase = vtb + (size_t)bh * 32768 + hi * 256 + l31 * 8;

    f32x16 ot;
    #pragma unroll
    for (int r = 0; r < 16; ++r) ot[r] = 0.f;
    float mrun = -1e30f, lrun = 0.f;

    bf16x8 kA0, kA1, vA0, vA1, kB0, kB1, vB0, vB1;
    LOADKV(kA0, kA1, vA0, vA1, 0);
    int kt = 0;
    for (;;) {
        if (kt < qt) LOADKV(kB0, kB1, vB0, vB1, kt + 1);
        TILE_COMPUTE(kA0, kA1, vA0, vA1, kt == qt);
        if (++kt > qt) break;
        if (kt < qt) LOADKV(kA0, kA1, vA0, vA1, kt + 1);
        TILE_COMPUTE(kB0, kB1, vB0, vB1, kt == qt);
        if (++kt > qt) break;
    }

    // epilogue: scale, transpose via LDS (stride 33 = conflict-free), RMW out
    const float inv = c_p / lrun;
    float* lt = lds_t[w];
    #pragma unroll
    for (int r = 0; r < 16; ++r) {
        const int d = (r & 3) + 8 * (r >> 2) + 4 * hi;
        lt[l31 * 33 + d] = ot[r] * inv;
    }
    __syncthreads();
    const int q0w = qt * 32;
    #pragma unroll
    for (int rr = 0; rr < 4; ++rr) {
        const int ql = rr * 8 + (lane >> 3);
        const int d0 = (lane & 7) * 4;
        const float* lp = &lt[ql * 33 + d0];
        float* op = out + ((size_t)b * S + q0w + ql) * D + h * 32 + d0;
        float4 cur = *(const float4*)op;
        cur.x += lp[0]; cur.y += lp[1]; cur.z += lp[2]; cur.w += lp[3];
        *(float4*)op = cur;
    }
}

// ---------------------------------------------------------------------------
extern "C" void kernel_launch(void* const* d_in, const int* in_sizes, int n_in,
                              void* d_out, int out_size, void* d_ws, size_t ws_size,
                              hipStream_t stream)
{
    (void)in_sizes; (void)n_in; (void)out_size; (void)ws_size;
    const float* query = (const float*)d_in[0];
    const float* key_  = (const float*)d_in[1];
    const float* value = (const float*)d_in[2];
    const float* rel   = (const float*)d_in[3];
    const float* tsp   = (const float*)d_in[4];
    const float* l1p   = (const float*)d_in[5];
    const float* l2p   = (const float*)d_in[6];
    const float* Wq    = (const float*)d_in[7];
    const float* bq    = (const float*)d_in[8];
    const float* Wk    = (const float*)d_in[9];
    const float* bk    = (const float*)d_in[10];
    const float* Wv    = (const float*)d_in[11];
    const float* bv    = (const float*)d_in[12];
    float* out = (float*)d_out;

    // ws: vp f32 [8MB] | qb bf16 [4MB] | kb bf16 [4MB] | vtb bf16 [4MB]
    float*  vp    = (float*)d_ws;
    ushort* qbuf  = (ushort*)((char*)d_ws + (8u  << 20));
    ushort* kbuf  = (ushort*)((char*)d_ws + (12u << 20));
    ushort* vtbuf = (ushort*)((char*)d_ws + (16u << 20));

    const float qscale = 1.4426950408889634f * 0.17677669529663687f; // log2e/sqrt(32)

    dim3 gproj(B * S / 64, D / 64);
    proj_gemm<0><<<gproj, 256, 0, stream>>>(query, Wq, bq, qscale, nullptr, qbuf);
    proj_gemm<0><<<gproj, 256, 0, stream>>>(key_,  Wk, bk, 1.0f,   nullptr, kbuf);
    proj_gemm<1><<<gproj, 256, 0, stream>>>(value, Wv, bv, 1.0f,   vp,      vtbuf);

    timerel_kernel<<<dim3(S / 32, B), 256, 0, stream>>>(tsp, rel, vp, l1p, l2p, out);

    flash_mfma<<<512, 256, 0, stream>>>(qbuf, kbuf, vtbuf, l1p, l2p, out);
}

// Round 3
// 124.770 us; speedup vs baseline: 4.6847x; 2.1016x over previous
//
#include <hip/hip_runtime.h>
#include <math.h>

constexpr int B = 8, S = 1024, D = 256, H = 8, HD = 32;

typedef __attribute__((ext_vector_type(8))) short bf16x8;
typedef __attribute__((ext_vector_type(16))) float f32x16;

__device__ __forceinline__ ushort f2bf(float f) {
    uint u = __float_as_uint(f);
    return (ushort)((u + 0x7FFFu + ((u >> 16) & 1u)) >> 16);
}
__device__ __forceinline__ uint cvtpk(float a, float b) {
    uint r;
    asm("v_cvt_pk_bf16_f32 %0, %1, %2" : "=v"(r) : "v"(a), "v"(b));
    return r;
}

// ---------------------------------------------------------------------------
// K1: projection GEMM  y[m,n] = sum_k x[m,k]*W[n,k] + bias[n]
// MODE 0: write bf16 in QK-fragment layout only (scaled).
// MODE 1: write f32 y + bf16 V^T fragment layout [b][h][t32][kc2][hi2][d32][j8]
// ---------------------------------------------------------------------------
template<int MODE>
__global__ __launch_bounds__(256) void proj_gemm(
    const float* __restrict__ x, const float* __restrict__ W,
    const float* __restrict__ bias, float scale,
    float* __restrict__ yf, ushort* __restrict__ yb)
{
    constexpr int K = D;
    __shared__ float xs[16][64];
    __shared__ float ws[16][64];
    const int m0 = blockIdx.x * 64;
    const int n0 = blockIdx.y * 64;
    const int tid = threadIdx.x;
    const int tm = tid >> 4, tn = tid & 15;
    const int lrow = tid >> 2;
    const int lcol = (tid & 3) * 4;
    float acc[4][4] = {};
    for (int k0 = 0; k0 < K; k0 += 16) {
        float4 xv = *(const float4*)&x[(size_t)(m0 + lrow) * K + k0 + lcol];
        float4 wv = *(const float4*)&W[(size_t)(n0 + lrow) * K + k0 + lcol];
        xs[lcol + 0][lrow] = xv.x; xs[lcol + 1][lrow] = xv.y;
        xs[lcol + 2][lrow] = xv.z; xs[lcol + 3][lrow] = xv.w;
        ws[lcol + 0][lrow] = wv.x; ws[lcol + 1][lrow] = wv.y;
        ws[lcol + 2][lrow] = wv.z; ws[lcol + 3][lrow] = wv.w;
        __syncthreads();
        #pragma unroll
        for (int kk = 0; kk < 16; ++kk) {
            float a[4], bv[4];
            *(float4*)a  = *(const float4*)&xs[kk][tm * 4];
            *(float4*)bv = *(const float4*)&ws[kk][tn * 4];
            #pragma unroll
            for (int i = 0; i < 4; ++i)
                #pragma unroll
                for (int j = 0; j < 4; ++j)
                    acc[i][j] += a[i] * bv[j];
        }
        __syncthreads();
    }
    const int mbase = m0 + tm * 4;
    const int nbase = n0 + tn * 4;
    float vals[4][4];
    #pragma unroll
    for (int i = 0; i < 4; ++i)
        #pragma unroll
        for (int j = 0; j < 4; ++j)
            vals[i][j] = acc[i][j] + bias[nbase + j];

    const int b_ = mbase >> 10;
    const int s  = mbase & 1023;
    const int h_ = nbase >> 5;

    if constexpr (MODE == 0) {
        const int hd = nbase & 31;
        const int c = hd >> 4, hig = (hd >> 3) & 1, j0 = hd & 7;
        size_t tb = ((((size_t)b_ * H + h_) * 32 + (s >> 5)) * 1024)
                    + c * 512 + hig * 256 + (size_t)(s & 31) * 8 + j0;
        #pragma unroll
        for (int i = 0; i < 4; ++i) {
            ushort4 pk = { f2bf(vals[i][0] * scale), f2bf(vals[i][1] * scale),
                           f2bf(vals[i][2] * scale), f2bf(vals[i][3] * scale) };
            *(ushort4*)&yb[tb + (size_t)i * 8] = pk;
        }
    } else {
        #pragma unroll
        for (int i = 0; i < 4; ++i) {
            float4 r4; r4.x = vals[i][0]; r4.y = vals[i][1];
                       r4.z = vals[i][2]; r4.w = vals[i][3];
            *(float4*)&yf[(size_t)(mbase + i) * D + nbase] = r4;
        }
        const int d0 = nbase & 31;
        const int kc = (s >> 4) & 1, hig = (s >> 3) & 1, j0 = s & 7;
        size_t tb = ((((size_t)b_ * H + h_) * 32 + (s >> 5)) * 1024)
                    + kc * 512 + hig * 256 + j0;
        #pragma unroll
        for (int jj = 0; jj < 4; ++jj) {
            ushort4 pk = { f2bf(vals[0][jj]), f2bf(vals[1][jj]),
                           f2bf(vals[2][jj]), f2bf(vals[3][jj]) };
            *(ushort4*)&yb[tb + (size_t)(d0 + jj) * 8] = pk;
        }
    }
}

// ---------------------------------------------------------------------------
// K1b: V column sums (for the all-masked-rel uniform row): cs[b][d] = sum_j V
// ---------------------------------------------------------------------------
__global__ __launch_bounds__(256) void colsum_kernel(
    const float* __restrict__ v, float* __restrict__ cs)
{
    const int b = blockIdx.x, jc = blockIdx.y;
    const int d = threadIdx.x;
    float s = 0.f;
    #pragma unroll 4
    for (int j = jc * 32; j < jc * 32 + 32; ++j)
        s += v[((size_t)b * S + j) * D + d];
    atomicAdd(&cs[b * D + d], s);
}

// ---------------------------------------------------------------------------
// K2: time+rel attention via MFMA (non-swapped: A=weights[i][k], B=V[k][d]).
// Block = 512 thr = 8 waves = (jq 0..3) x (dh 0..1) over one (b, 32-row tile).
// Unnormalized bf16 weight fragments; f32 row-sums; normalize in epilogue.
// ---------------------------------------------------------------------------
__global__ __launch_bounds__(512, 2) void timerel_mfma(
    const float* __restrict__ ts, const float* __restrict__ rel,
    const ushort* __restrict__ vtb, const float* __restrict__ colsum,
    const float* __restrict__ l1p, const float* __restrict__ l2p,
    float* __restrict__ out)
{
    __shared__ float cbuf[3][2][4][64][17];       // [jq-1][dh][t][lane][16+pad]
    __shared__ float rsum[2][4][32];              // [part][jq][i]
    __shared__ float normt[32], normr[32], nuni[32];

    const int b  = blockIdx.y;
    const int i0 = blockIdx.x * 32;
    const int w = threadIdx.x >> 6, lane = threadIdx.x & 63;
    const int jq = w & 3, dh = w >> 2;
    const int l31 = lane & 31, hi = lane >> 5;
    const int hi8 = hi * 8;
    const int i = i0 + l31;

    const float* tsrow  = ts  + ((size_t)b * S + i) * S + hi8;
    const float* relrow = rel + ((size_t)b * S + i) * S + hi8;
    const ushort* vtbase = vtb + ((size_t)b * 8 + dh * 4) * 32768 + hi * 256 + l31 * 8;

    f32x16 accT[4], accR[4];
    #pragma unroll
    for (int t = 0; t < 4; ++t)
        #pragma unroll
        for (int r = 0; r < 16; ++r) { accT[t][r] = 0.f; accR[t][r] = 0.f; }
    float st = 0.f, sr = 0.f;

    const int ks0 = jq * 16;
    #pragma unroll 2
    for (int ks = ks0; ks < ks0 + 16; ++ks) {
        const int js = ks * 16;
        const bool anyPast = (js <= i0 + 31);
        const bool allPast = (js + 15 <= i0);

        bf16x8 vf[4];
        #pragma unroll
        for (int t = 0; t < 4; ++t)
            vf[t] = *(const bf16x8*)(vtbase + (size_t)t * 32768 + (size_t)ks * 512);

        if (anyPast) {
            float tv[8];
            *(float4*)&tv[0] = *(const float4*)(tsrow + js);
            *(float4*)&tv[4] = *(const float4*)(tsrow + js + 4);
            uint wp[4];
            #pragma unroll
            for (int q = 0; q < 4; ++q) {
                float w0 = __expf(__expf(-fabsf(tv[2 * q])));
                float w1 = __expf(__expf(-fabsf(tv[2 * q + 1])));
                if (!allPast) {
                    w0 = (js + hi8 + 2 * q     <= i) ? w0 : 0.f;
                    w1 = (js + hi8 + 2 * q + 1 <= i) ? w1 : 0.f;
                }
                st += w0 + w1;
                wp[q] = cvtpk(w0, w1);
            }
            bf16x8 wA = __builtin_bit_cast(bf16x8, *(uint4*)wp);
            #pragma unroll
            for (int t = 0; t < 4; ++t)
                accT[t] = __builtin_amdgcn_mfma_f32_32x32x16_bf16(wA, vf[t], accT[t], 0, 0, 0);
        }
        if (!allPast) {
            float rv[8];
            *(float4*)&rv[0] = *(const float4*)(relrow + js);
            *(float4*)&rv[4] = *(const float4*)(relrow + js + 4);
            uint wp[4];
            #pragma unroll
            for (int q = 0; q < 4; ++q) {
                float r0 = rv[2 * q], r1 = rv[2 * q + 1];
                float w0 = (r0 != 0.f) ? __expf(r0) : 0.f;
                float w1 = (r1 != 0.f) ? __expf(r1) : 0.f;
                if (anyPast) {
                    w0 = (js + hi8 + 2 * q     > i) ? w0 : 0.f;
                    w1 = (js + hi8 + 2 * q + 1 > i) ? w1 : 0.f;
                }
                sr += w0 + w1;
                wp[q] = cvtpk(w0, w1);
            }
            bf16x8 wA = __builtin_bit_cast(bf16x8, *(uint4*)wp);
            #pragma unroll
            for (int t = 0; t < 4; ++t)
                accR[t] = __builtin_amdgcn_mfma_f32_32x32x16_bf16(wA, vf[t], accR[t], 0, 0, 0);
        }
    }

    // ---- row-sum partials ----
    st += __shfl_xor(st, 32);
    sr += __shfl_xor(sr, 32);
    if (dh == 0 && hi == 0) { rsum[0][jq][l31] = st; rsum[1][jq][l31] = sr; }

    // ---- combine round 1: time part ----
    if (jq != 0) {
        #pragma unroll
        for (int t = 0; t < 4; ++t)
            #pragma unroll
            for (int q = 0; q < 4; ++q)
                *(float4*)&cbuf[jq - 1][dh][t][lane][q * 4] =
                    make_float4(accT[t][q*4], accT[t][q*4+1], accT[t][q*4+2], accT[t][q*4+3]);
    }
    __syncthreads();
    if (w == 0 && hi == 0) {
        const float l1 = l1p[0], l2 = l2p[0];
        float stt = rsum[0][0][l31] + rsum[0][1][l31] + rsum[0][2][l31] + rsum[0][3][l31];
        float srt = rsum[1][0][l31] + rsum[1][1][l31] + rsum[1][2][l31] + rsum[1][3][l31];
        normt[l31] = (1.f - l1) * l2 / stt;
        normr[l31] = (srt > 0.5f) ? (l1 / srt) : 0.f;
        nuni[l31]  = (srt > 0.5f) ? 0.f : (l1 / (float)S);
    }
    if (jq == 0) {
        #pragma unroll
        for (int t = 0; t < 4; ++t)
            #pragma unroll
            for (int q = 0; q < 3; ++q)
                #pragma unroll
                for (int r = 0; r < 16; ++r)
                    accT[t][r] += cbuf[q][dh][t][lane][r];
    }
    __syncthreads();
    // ---- combine round 2: rel part ----
    if (jq != 0) {
        #pragma unroll
        for (int t = 0; t < 4; ++t)
            #pragma unroll
            for (int q = 0; q < 4; ++q)
                *(float4*)&cbuf[jq - 1][dh][t][lane][q * 4] =
                    make_float4(accR[t][q*4], accR[t][q*4+1], accR[t][q*4+2], accR[t][q*4+3]);
    }
    __syncthreads();
    if (jq == 0) {
        #pragma unroll
        for (int t = 0; t < 4; ++t)
            #pragma unroll
            for (int q = 0; q < 3; ++q)
                #pragma unroll
                for (int r = 0; r < 16; ++r)
                    accR[t][r] += cbuf[q][dh][t][lane][r];

        // ---- epilogue: normalize + uniform-row fixup, write out ----
        #pragma unroll
        for (int t = 0; t < 4; ++t) {
            const int d = (dh * 4 + t) * 32 + l31;
            const float cv = colsum[b * D + d];
            float* obase = out + ((size_t)b * S + i0) * D + d;
            #pragma unroll
            for (int r = 0; r < 16; ++r) {
                const int row = (r & 3) + 8 * (r >> 2) + 4 * hi;
                obase[(size_t)row * D] =
                    accT[t][r] * normt[row] + accR[t][r] * normr[row] + nuni[row] * cv;
            }
        }
    }
}

// ---------------------------------------------------------------------------
// K3: MFMA flash attention (swapped operands), out += c_p * softmax(QK^T)V
// ---------------------------------------------------------------------------
#define LOADKV(K0, K1, V0, V1, KT) do { \
    const ushort* kp_ = kbase + (size_t)(KT) * 1024; \
    const ushort* vp_ = vbase + (size_t)(KT) * 1024; \
    K0 = *(const bf16x8*)kp_;        K1 = *(const bf16x8*)(kp_ + 512); \
    V0 = *(const bf16x8*)vp_;        V1 = *(const bf16x8*)(vp_ + 512); \
} while (0)

#define TILE_COMPUTE(K0, K1, V0, V1, ISDIAG) do { \
    f32x16 st; \
    _Pragma("unroll") for (int r = 0; r < 16; ++r) st[r] = 0.f; \
    st = __builtin_amdgcn_mfma_f32_32x32x16_bf16(K0, qf0, st, 0, 0, 0); \
    st = __builtin_amdgcn_mfma_f32_32x32x16_bf16(K1, qf1, st, 0, 0, 0); \
    if (ISDIAG) { \
        _Pragma("unroll") for (int r = 0; r < 16; ++r) \
            if (((r & 3) + 8 * (r >> 2) + 4 * hi) > l31) st[r] = -1e30f; \
    } \
    float pmax = st[0]; \
    _Pragma("unroll") for (int r = 1; r < 16; ++r) pmax = fmaxf(pmax, st[r]); \
    pmax = fmaxf(pmax, __shfl_xor(pmax, 32)); \
    const float mnew = fmaxf(mrun, pmax); \
    const float csc = exp2f(mrun - mnew); \
    float p[16]; float psum = 0.f; \
    _Pragma("unroll") for (int r = 0; r < 16; ++r) { p[r] = exp2f(st[r] - mnew); psum += p[r]; } \
    psum += __shfl_xor(psum, 32); \
    lrun = lrun * csc + psum; mrun = mnew; \
    _Pragma("unroll") for (int r = 0; r < 16; ++r) ot[r] *= csc; \
    uint wa0 = cvtpk(p[0], p[1]),   wa1 = cvtpk(p[2], p[3]); \
    uint wb0 = cvtpk(p[4], p[5]),   wb1 = cvtpk(p[6], p[7]); \
    uint wa2 = cvtpk(p[8], p[9]),   wa3 = cvtpk(p[10], p[11]); \
    uint wb2 = cvtpk(p[12], p[13]), wb3 = cvtpk(p[14], p[15]); \
    uint t0 = (uint)__shfl_xor((int)wb0, 32), u0 = (uint)__shfl_xor((int)wa0, 32); \
    uint t1 = (uint)__shfl_xor((int)wb1, 32), u1 = (uint)__shfl_xor((int)wa1, 32); \
    uint t2 = (uint)__shfl_xor((int)wb2, 32), u2 = (uint)__shfl_xor((int)wa2, 32); \
    uint t3 = (uint)__shfl_xor((int)wb3, 32), u3 = (uint)__shfl_xor((int)wa3, 32); \
    uint4 pa0i = { hi ? t0 : wa0, hi ? t1 : wa1, hi ? wb0 : u0, hi ? wb1 : u1 }; \
    uint4 pa1i = { hi ? t2 : wa2, hi ? t3 : wa3, hi ? wb2 : u2, hi ? wb3 : u3 }; \
    bf16x8 pa0 = __builtin_bit_cast(bf16x8, pa0i); \
    bf16x8 pa1 = __builtin_bit_cast(bf16x8, pa1i); \
    ot = __builtin_amdgcn_mfma_f32_32x32x16_bf16(V0, pa0, ot, 0, 0, 0); \
    ot = __builtin_amdgcn_mfma_f32_32x32x16_bf16(V1, pa1, ot, 0, 0, 0); \
} while (0)

__global__ __launch_bounds__(256) void flash_mfma(
    const ushort* __restrict__ qb, const ushort* __restrict__ kb,
    const ushort* __restrict__ vtb, const float* __restrict__ l1p,
    const float* __restrict__ l2p, float* __restrict__ out)
{
    __shared__ float lds_t[4][32 * 33];
    const int id = blockIdx.x;
    const int halfg = id >> 8, rr_ = id & 255;
    const int qraw = rr_ >> 5;
    const int qblk = halfg ? (7 - qraw) : qraw;
    const int bh = (rr_ & 31) | (halfg << 5);
    const int b = bh >> 3, h = bh & 7;
    const int w = threadIdx.x >> 6, lane = threadIdx.x & 63;
    const int l31 = lane & 31, hi = lane >> 5;
    const int qt = qblk * 4 + w;
    const float c_p = (1.f - l1p[0]) * (1.f - l2p[0]);

    const ushort* qp_ = qb + ((size_t)bh * 32 + qt) * 1024 + hi * 256 + l31 * 8;
    const bf16x8 qf0 = *(const bf16x8*)qp_;
    const bf16x8 qf1 = *(const bf16x8*)(qp_ + 512);
    const ushort* kbase = kb  + (size_t)bh * 32768 + hi * 256 + l31 * 8;
    const ushort* vbase = vtb + (size_t)bh * 32768 + hi * 256 + l31 * 8;

    f32x16 ot;
    #pragma unroll
    for (int r = 0; r < 16; ++r) ot[r] = 0.f;
    float mrun = -1e30f, lrun = 0.f;

    bf16x8 kA0, kA1, vA0, vA1, kB0, kB1, vB0, vB1;
    LOADKV(kA0, kA1, vA0, vA1, 0);
    int kt = 0;
    for (;;) {
        if (kt < qt) LOADKV(kB0, kB1, vB0, vB1, kt + 1);
        TILE_COMPUTE(kA0, kA1, vA0, vA1, kt == qt);
        if (++kt > qt) break;
        if (kt < qt) LOADKV(kA0, kA1, vA0, vA1, kt + 1);
        TILE_COMPUTE(kB0, kB1, vB0, vB1, kt == qt);
        if (++kt > qt) break;
    }

    const float inv = c_p / lrun;
    float* lt = lds_t[w];
    #pragma unroll
    for (int r = 0; r < 16; ++r) {
        const int d = (r & 3) + 8 * (r >> 2) + 4 * hi;
        lt[l31 * 33 + d] = ot[r] * inv;
    }
    __syncthreads();
    const int q0w = qt * 32;
    #pragma unroll
    for (int rr = 0; rr < 4; ++rr) {
        const int ql = rr * 8 + (lane >> 3);
        const int d0 = (lane & 7) * 4;
        const float* lp = &lt[ql * 33 + d0];
        float* op = out + ((size_t)b * S + q0w + ql) * D + h * 32 + d0;
        float4 cur = *(const float4*)op;
        cur.x += lp[0]; cur.y += lp[1]; cur.z += lp[2]; cur.w += lp[3];
        *(float4*)op = cur;
    }
}

// ---------------------------------------------------------------------------
extern "C" void kernel_launch(void* const* d_in, const int* in_sizes, int n_in,
                              void* d_out, int out_size, void* d_ws, size_t ws_size,
                              hipStream_t stream)
{
    (void)in_sizes; (void)n_in; (void)out_size; (void)ws_size;
    const float* query = (const float*)d_in[0];
    const float* key_  = (const float*)d_in[1];
    const float* value = (const float*)d_in[2];
    const float* rel   = (const float*)d_in[3];
    const float* tsp   = (const float*)d_in[4];
    const float* l1p   = (const float*)d_in[5];
    const float* l2p   = (const float*)d_in[6];
    const float* Wq    = (const float*)d_in[7];
    const float* bq    = (const float*)d_in[8];
    const float* Wk    = (const float*)d_in[9];
    const float* bk    = (const float*)d_in[10];
    const float* Wv    = (const float*)d_in[11];
    const float* bv    = (const float*)d_in[12];
    float* out = (float*)d_out;

    // ws: vp f32 [8MB] | qb [4MB] | kb [4MB] | vtb [4MB] | colsum [8KB]
    float*  vp    = (float*)d_ws;
    ushort* qbuf  = (ushort*)((char*)d_ws + (8u  << 20));
    ushort* kbuf  = (ushort*)((char*)d_ws + (12u << 20));
    ushort* vtbuf = (ushort*)((char*)d_ws + (16u << 20));
    float*  csum  = (float*)((char*)d_ws + (20u << 20));

    const float qscale = 1.4426950408889634f * 0.17677669529663687f; // log2e/sqrt(32)

    dim3 gproj(B * S / 64, D / 64);
    proj_gemm<0><<<gproj, 256, 0, stream>>>(query, Wq, bq, qscale, nullptr, qbuf);
    proj_gemm<0><<<gproj, 256, 0, stream>>>(key_,  Wk, bk, 1.0f,   nullptr, kbuf);
    proj_gemm<1><<<gproj, 256, 0, stream>>>(value, Wv, bv, 1.0f,   vp,      vtbuf);

    hipMemsetAsync(csum, 0, B * D * sizeof(float), stream);
    colsum_kernel<<<dim3(B, S / 32), 256, 0, stream>>>(vp, csum);

    timerel_mfma<<<dim3(S / 32, B), 512, 0, stream>>>(
        tsp, rel, vtbuf, csum, l1p, l2p, out);

    flash_mfma<<<512, 256, 0, stream>>>(qbuf, kbuf, vtbuf, l1p, l2p, out);
}

// Round 4
// 85.457 us; speedup vs baseline: 6.8398x; 1.4600x over previous
//
#include <hip/hip_runtime.h>
#include <math.h>

constexpr int B = 8, S = 1024, D = 256, H = 8, HD = 32;

typedef __attribute__((ext_vector_type(8))) short bf16x8;
typedef __attribute__((ext_vector_type(16))) float f32x16;

__device__ __forceinline__ uint cvtpk(float a, float b) {
    uint r;
    asm("v_cvt_pk_bf16_f32 %0, %1, %2" : "=v"(r) : "v"(a), "v"(b));
    return r;
}
__device__ __forceinline__ uint shfl32(uint x) {
    return (uint)__shfl_xor((int)x, 32);
}

// ---------------------------------------------------------------------------
// K0: zero the colsum accumulator (replaces hipMemsetAsync: 39us fill path!)
// ---------------------------------------------------------------------------
__global__ void zero_csum(float* __restrict__ p) {
    p[blockIdx.x * 256 + threadIdx.x] = 0.f;
}

// ---------------------------------------------------------------------------
// K1: fused MFMA projection. blockIdx.y = matrix (0=Q,1=K,2=V).
// Block: 512 thr = 8 waves = 8 heads; handles 2 s-tiles (32 rows each).
// Q/K: C^T = W x^T (lane=s, regs=d)  -> Q/K fragment buffers (repack+store).
// V  : C = x W^T  (lane=d, regs=s)   -> V^T fragment buffer + colsum atomics.
// x staged in LDS as [kc16][hig2][jh2][s32][j4] bf16 (8B ops, 2-way banks=free).
// ---------------------------------------------------------------------------
__global__ __launch_bounds__(512, 4) void proj_mfma(
    const float* __restrict__ query, const float* __restrict__ key_,
    const float* __restrict__ value,
    const float* __restrict__ Wq, const float* __restrict__ Wk,
    const float* __restrict__ Wv,
    const float* __restrict__ bq, const float* __restrict__ bk,
    const float* __restrict__ bv, float qscale,
    ushort* __restrict__ qbuf, ushort* __restrict__ kbuf,
    ushort* __restrict__ vtbuf, float* __restrict__ csum)
{
    __shared__ ushort xf[8192];          // 16KB staged x tile (frag order)
    __shared__ float bias_lds[256];

    const int m = blockIdx.y;
    const int tid = threadIdx.x;
    const int w = tid >> 6, lane = tid & 63;
    const int l31 = lane & 31, hi = lane >> 5;
    const int h = w;

    const float* xsrc = (m == 0) ? query : (m == 1) ? key_ : value;
    const float* Wsrc = (m == 0) ? Wq : (m == 1) ? Wk : Wv;
    const float* bsrc = (m == 0) ? bq : (m == 1) ? bk : bv;
    ushort* yb = (m == 0) ? qbuf : (m == 1) ? kbuf : vtbuf;
    const float wscale = (m == 0) ? qscale : 1.0f;

    // bias (scaled) -> LDS
    if (tid < 256) bias_lds[tid] = bsrc[tid] * wscale;

    // W fragments -> registers (lane l31 = d within head, hi selects k-half)
    bf16x8 wf[16];
    {
        const float* wrow = Wsrc + ((size_t)(h * 32 + l31)) * 256 + hi * 8;
        #pragma unroll
        for (int kc = 0; kc < 16; ++kc) {
            float4 a = *(const float4*)(wrow + kc * 16);
            float4 b = *(const float4*)(wrow + kc * 16 + 4);
            uint4 p;
            p.x = cvtpk(a.x * wscale, a.y * wscale);
            p.y = cvtpk(a.z * wscale, a.w * wscale);
            p.z = cvtpk(b.x * wscale, b.y * wscale);
            p.w = cvtpk(b.z * wscale, b.w * wscale);
            wf[kc] = __builtin_bit_cast(bf16x8, p);
        }
    }

    const int sst = tid & 31, skc = tid >> 5;    // staging role: (s, kchunk)

    for (int it = 0; it < 2; ++it) {
        const int stile = blockIdx.x * 2 + it;   // global 32-row tile 0..255
        const int b_ = stile >> 5, t32 = stile & 31;

        __syncthreads();
        // ---- stage x tile (32 s x 256 k) as bf16 fragments ----
        {
            const float* xrow = xsrc + ((size_t)(stile * 32 + sst)) * 256 + skc * 16;
            float4 a0 = *(const float4*)(xrow + 0);
            float4 a1 = *(const float4*)(xrow + 4);
            float4 a2 = *(const float4*)(xrow + 8);
            float4 a3 = *(const float4*)(xrow + 12);
            uint2 w01 = { cvtpk(a0.x, a0.y), cvtpk(a0.z, a0.w) };  // hig0 jh0
            uint2 w23 = { cvtpk(a1.x, a1.y), cvtpk(a1.z, a1.w) };  // hig0 jh1
            uint2 w45 = { cvtpk(a2.x, a2.y), cvtpk(a2.z, a2.w) };  // hig1 jh0
            uint2 w67 = { cvtpk(a3.x, a3.y), cvtpk(a3.z, a3.w) };  // hig1 jh1
            ushort* base = xf + skc * 512 + sst * 4;
            *(uint2*)(base +   0) = w01;
            *(uint2*)(base + 128) = w23;
            *(uint2*)(base + 256) = w45;
            *(uint2*)(base + 384) = w67;
        }
        __syncthreads();

        // ---- 16 MFMA over K=256 ----
        f32x16 acc;
        #pragma unroll
        for (int r = 0; r < 16; ++r) acc[r] = 0.f;
        #pragma unroll
        for (int kc = 0; kc < 16; ++kc) {
            const ushort* rb = xf + kc * 512 + hi * 256 + l31 * 4;
            uint2 lo = *(const uint2*)rb;
            uint2 hj = *(const uint2*)(rb + 128);
            uint4 xw = { lo.x, lo.y, hj.x, hj.y };
            bf16x8 xfrag = __builtin_bit_cast(bf16x8, xw);
            if (m < 2)
                acc = __builtin_amdgcn_mfma_f32_32x32x16_bf16(wf[kc], xfrag, acc, 0, 0, 0);
            else
                acc = __builtin_amdgcn_mfma_f32_32x32x16_bf16(xfrag, wf[kc], acc, 0, 0, 0);
        }

        // ---- bias ----
        if (m < 2) {
            // acc[r] = y^T[d(r)][s=l31]; bias depends on d(r)
            #pragma unroll
            for (int r = 0; r < 16; ++r)
                acc[r] += bias_lds[h * 32 + (r & 3) + 8 * (r >> 2) + 4 * hi];
        } else {
            const float bl = bias_lds[h * 32 + l31];   // lane = d
            #pragma unroll
            for (int r = 0; r < 16; ++r) acc[r] += bl;
            // colsum: sum over the 32 s-rows of this tile for lane's d
            float cp = 0.f;
            #pragma unroll
            for (int r = 0; r < 16; ++r) cp += acc[r];
            cp += __shfl_xor(cp, 32);
            if (hi == 0)
                atomicAdd(&csum[b_ * D + h * 32 + l31], cp);
        }

        // ---- repack (identical recipe to flash P-frag) + store ----
        uint wa0 = cvtpk(acc[0], acc[1]),   wa1 = cvtpk(acc[2], acc[3]);
        uint wb0 = cvtpk(acc[4], acc[5]),   wb1 = cvtpk(acc[6], acc[7]);
        uint wa2 = cvtpk(acc[8], acc[9]),   wa3 = cvtpk(acc[10], acc[11]);
        uint wb2 = cvtpk(acc[12], acc[13]), wb3 = cvtpk(acc[14], acc[15]);
        uint t0 = shfl32(wb0), u0 = shfl32(wa0);
        uint t1 = shfl32(wb1), u1 = shfl32(wa1);
        uint t2 = shfl32(wb2), u2 = shfl32(wa2);
        uint t3 = shfl32(wb3), u3 = shfl32(wa3);
        uint4 p0 = { hi ? t0 : wa0, hi ? t1 : wa1, hi ? wb0 : u0, hi ? wb1 : u1 };
        uint4 p1 = { hi ? t2 : wa2, hi ? t3 : wa3, hi ? wb2 : u2, hi ? wb3 : u3 };
        ushort* dst = yb + (((size_t)b_ * H + h) * 32 + t32) * 1024 + hi * 256 + l31 * 8;
        *(uint4*)dst = p0;
        *(uint4*)(dst + 512) = p1;
    }
}

// ---------------------------------------------------------------------------
// K2: time+rel attention via MFMA (non-swapped: A=weights[i][k], B=V[k][d]).
// ---------------------------------------------------------------------------
__global__ __launch_bounds__(512, 2) void timerel_mfma(
    const float* __restrict__ ts, const float* __restrict__ rel,
    const ushort* __restrict__ vtb, const float* __restrict__ colsum,
    const float* __restrict__ l1p, const float* __restrict__ l2p,
    float* __restrict__ out)
{
    __shared__ float cbuf[3][2][4][64][17];
    __shared__ float rsum[2][4][32];
    __shared__ float normt[32], normr[32], nuni[32];

    const int b  = blockIdx.y;
    const int i0 = blockIdx.x * 32;
    const int w = threadIdx.x >> 6, lane = threadIdx.x & 63;
    const int jq = w & 3, dh = w >> 2;
    const int l31 = lane & 31, hi = lane >> 5;
    const int hi8 = hi * 8;
    const int i = i0 + l31;

    const float* tsrow  = ts  + ((size_t)b * S + i) * S + hi8;
    const float* relrow = rel + ((size_t)b * S + i) * S + hi8;
    const ushort* vtbase = vtb + ((size_t)b * 8 + dh * 4) * 32768 + hi * 256 + l31 * 8;

    f32x16 accT[4], accR[4];
    #pragma unroll
    for (int t = 0; t < 4; ++t)
        #pragma unroll
        for (int r = 0; r < 16; ++r) { accT[t][r] = 0.f; accR[t][r] = 0.f; }
    float st = 0.f, sr = 0.f;

    const int ks0 = jq * 16;
    #pragma unroll 2
    for (int ks = ks0; ks < ks0 + 16; ++ks) {
        const int js = ks * 16;
        const bool anyPast = (js <= i0 + 31);
        const bool allPast = (js + 15 <= i0);

        bf16x8 vf[4];
        #pragma unroll
        for (int t = 0; t < 4; ++t)
            vf[t] = *(const bf16x8*)(vtbase + (size_t)t * 32768 + (size_t)ks * 512);

        if (anyPast) {
            float tv[8];
            *(float4*)&tv[0] = *(const float4*)(tsrow + js);
            *(float4*)&tv[4] = *(const float4*)(tsrow + js + 4);
            uint wp[4];
            #pragma unroll
            for (int q = 0; q < 4; ++q) {
                float w0 = __expf(__expf(-fabsf(tv[2 * q])));
                float w1 = __expf(__expf(-fabsf(tv[2 * q + 1])));
                if (!allPast) {
                    w0 = (js + hi8 + 2 * q     <= i) ? w0 : 0.f;
                    w1 = (js + hi8 + 2 * q + 1 <= i) ? w1 : 0.f;
                }
                st += w0 + w1;
                wp[q] = cvtpk(w0, w1);
            }
            bf16x8 wA = __builtin_bit_cast(bf16x8, *(uint4*)wp);
            #pragma unroll
            for (int t = 0; t < 4; ++t)
                accT[t] = __builtin_amdgcn_mfma_f32_32x32x16_bf16(wA, vf[t], accT[t], 0, 0, 0);
        }
        if (!allPast) {
            float rv[8];
            *(float4*)&rv[0] = *(const float4*)(relrow + js);
            *(float4*)&rv[4] = *(const float4*)(relrow + js + 4);
            uint wp[4];
            #pragma unroll
            for (int q = 0; q < 4; ++q) {
                float r0 = rv[2 * q], r1 = rv[2 * q + 1];
                float w0 = (r0 != 0.f) ? __expf(r0) : 0.f;
                float w1 = (r1 != 0.f) ? __expf(r1) : 0.f;
                if (anyPast) {
                    w0 = (js + hi8 + 2 * q     > i) ? w0 : 0.f;
                    w1 = (js + hi8 + 2 * q + 1 > i) ? w1 : 0.f;
                }
                sr += w0 + w1;
                wp[q] = cvtpk(w0, w1);
            }
            bf16x8 wA = __builtin_bit_cast(bf16x8, *(uint4*)wp);
            #pragma unroll
            for (int t = 0; t < 4; ++t)
                accR[t] = __builtin_amdgcn_mfma_f32_32x32x16_bf16(wA, vf[t], accR[t], 0, 0, 0);
        }
    }

    st += __shfl_xor(st, 32);
    sr += __shfl_xor(sr, 32);
    if (dh == 0 && hi == 0) { rsum[0][jq][l31] = st; rsum[1][jq][l31] = sr; }

    if (jq != 0) {
        #pragma unroll
        for (int t = 0; t < 4; ++t)
            #pragma unroll
            for (int q = 0; q < 4; ++q)
                *(float4*)&cbuf[jq - 1][dh][t][lane][q * 4] =
                    make_float4(accT[t][q*4], accT[t][q*4+1], accT[t][q*4+2], accT[t][q*4+3]);
    }
    __syncthreads();
    if (w == 0 && hi == 0) {
        const float l1 = l1p[0], l2 = l2p[0];
        float stt = rsum[0][0][l31] + rsum[0][1][l31] + rsum[0][2][l31] + rsum[0][3][l31];
        float srt = rsum[1][0][l31] + rsum[1][1][l31] + rsum[1][2][l31] + rsum[1][3][l31];
        normt[l31] = (1.f - l1) * l2 / stt;
        normr[l31] = (srt > 0.5f) ? (l1 / srt) : 0.f;
        nuni[l31]  = (srt > 0.5f) ? 0.f : (l1 / (float)S);
    }
    if (jq == 0) {
        #pragma unroll
        for (int t = 0; t < 4; ++t)
            #pragma unroll
            for (int q = 0; q < 3; ++q)
                #pragma unroll
                for (int r = 0; r < 16; ++r)
                    accT[t][r] += cbuf[q][dh][t][lane][r];
    }
    __syncthreads();
    if (jq != 0) {
        #pragma unroll
        for (int t = 0; t < 4; ++t)
            #pragma unroll
            for (int q = 0; q < 4; ++q)
                *(float4*)&cbuf[jq - 1][dh][t][lane][q * 4] =
                    make_float4(accR[t][q*4], accR[t][q*4+1], accR[t][q*4+2], accR[t][q*4+3]);
    }
    __syncthreads();
    if (jq == 0) {
        #pragma unroll
        for (int t = 0; t < 4; ++t)
            #pragma unroll
            for (int q = 0; q < 3; ++q)
                #pragma unroll
                for (int r = 0; r < 16; ++r)
                    accR[t][r] += cbuf[q][dh][t][lane][r];

        #pragma unroll
        for (int t = 0; t < 4; ++t) {
            const int d = (dh * 4 + t) * 32 + l31;
            const float cv = colsum[b * D + d];
            float* obase = out + ((size_t)b * S + i0) * D + d;
            #pragma unroll
            for (int r = 0; r < 16; ++r) {
                const int row = (r & 3) + 8 * (r >> 2) + 4 * hi;
                obase[(size_t)row * D] =
                    accT[t][r] * normt[row] + accR[t][r] * normr[row] + nuni[row] * cv;
            }
        }
    }
}

// ---------------------------------------------------------------------------
// K3: MFMA flash attention (swapped operands), out += c_p * softmax(QK^T)V
// ---------------------------------------------------------------------------
#define LOADKV(K0, K1, V0, V1, KT) do { \
    const ushort* kp_ = kbase + (size_t)(KT) * 1024; \
    const ushort* vp_ = vbase + (size_t)(KT) * 1024; \
    K0 = *(const bf16x8*)kp_;        K1 = *(const bf16x8*)(kp_ + 512); \
    V0 = *(const bf16x8*)vp_;        V1 = *(const bf16x8*)(vp_ + 512); \
} while (0)

#define TILE_COMPUTE(K0, K1, V0, V1, ISDIAG) do { \
    f32x16 st; \
    _Pragma("unroll") for (int r = 0; r < 16; ++r) st[r] = 0.f; \
    st = __builtin_amdgcn_mfma_f32_32x32x16_bf16(K0, qf0, st, 0, 0, 0); \
    st = __builtin_amdgcn_mfma_f32_32x32x16_bf16(K1, qf1, st, 0, 0, 0); \
    if (ISDIAG) { \
        _Pragma("unroll") for (int r = 0; r < 16; ++r) \
            if (((r & 3) + 8 * (r >> 2) + 4 * hi) > l31) st[r] = -1e30f; \
    } \
    float pmax = st[0]; \
    _Pragma("unroll") for (int r = 1; r < 16; ++r) pmax = fmaxf(pmax, st[r]); \
    pmax = fmaxf(pmax, __shfl_xor(pmax, 32)); \
    const float mnew = fmaxf(mrun, pmax); \
    const float csc = exp2f(mrun - mnew); \
    float p[16]; float psum = 0.f; \
    _Pragma("unroll") for (int r = 0; r < 16; ++r) { p[r] = exp2f(st[r] - mnew); psum += p[r]; } \
    psum += __shfl_xor(psum, 32); \
    lrun = lrun * csc + psum; mrun = mnew; \
    _Pragma("unroll") for (int r = 0; r < 16; ++r) ot[r] *= csc; \
    uint wa0 = cvtpk(p[0], p[1]),   wa1 = cvtpk(p[2], p[3]); \
    uint wb0 = cvtpk(p[4], p[5]),   wb1 = cvtpk(p[6], p[7]); \
    uint wa2 = cvtpk(p[8], p[9]),   wa3 = cvtpk(p[10], p[11]); \
    uint wb2 = cvtpk(p[12], p[13]), wb3 = cvtpk(p[14], p[15]); \
    uint t0 = shfl32(wb0), u0 = shfl32(wa0); \
    uint t1 = shfl32(wb1), u1 = shfl32(wa1); \
    uint t2 = shfl32(wb2), u2 = shfl32(wa2); \
    uint t3 = shfl32(wb3), u3 = shfl32(wa3); \
    uint4 pa0i = { hi ? t0 : wa0, hi ? t1 : wa1, hi ? wb0 : u0, hi ? wb1 : u1 }; \
    uint4 pa1i = { hi ? t2 : wa2, hi ? t3 : wa3, hi ? wb2 : u2, hi ? wb3 : u3 }; \
    bf16x8 pa0 = __builtin_bit_cast(bf16x8, pa0i); \
    bf16x8 pa1 = __builtin_bit_cast(bf16x8, pa1i); \
    ot = __builtin_amdgcn_mfma_f32_32x32x16_bf16(V0, pa0, ot, 0, 0, 0); \
    ot = __builtin_amdgcn_mfma_f32_32x32x16_bf16(V1, pa1, ot, 0, 0, 0); \
} while (0)

__global__ __launch_bounds__(256) void flash_mfma(
    const ushort* __restrict__ qb, const ushort* __restrict__ kb,
    const ushort* __restrict__ vtb, const float* __restrict__ l1p,
    const float* __restrict__ l2p, float* __restrict__ out)
{
    __shared__ float lds_t[4][32 * 33];
    const int id = blockIdx.x;
    const int halfg = id >> 8, rr_ = id & 255;
    const int qraw = rr_ >> 5;
    const int qblk = halfg ? (7 - qraw) : qraw;
    const int bh = (rr_ & 31) | (halfg << 5);
    const int b = bh >> 3, h = bh & 7;
    const int w = threadIdx.x >> 6, lane = threadIdx.x & 63;
    const int l31 = lane & 31, hi = lane >> 5;
    const int qt = qblk * 4 + w;
    const float c_p = (1.f - l1p[0]) * (1.f - l2p[0]);

    const ushort* qp_ = qb + ((size_t)bh * 32 + qt) * 1024 + hi * 256 + l31 * 8;
    const bf16x8 qf0 = *(const bf16x8*)qp_;
    const bf16x8 qf1 = *(const bf16x8*)(qp_ + 512);
    const ushort* kbase = kb  + (size_t)bh * 32768 + hi * 256 + l31 * 8;
    const ushort* vbase = vtb + (size_t)bh * 32768 + hi * 256 + l31 * 8;

    f32x16 ot;
    #pragma unroll
    for (int r = 0; r < 16; ++r) ot[r] = 0.f;
    float mrun = -1e30f, lrun = 0.f;

    bf16x8 kA0, kA1, vA0, vA1, kB0, kB1, vB0, vB1;
    LOADKV(kA0, kA1, vA0, vA1, 0);
    int kt = 0;
    for (;;) {
        if (kt < qt) LOADKV(kB0, kB1, vB0, vB1, kt + 1);
        TILE_COMPUTE(kA0, kA1, vA0, vA1, kt == qt);
        if (++kt > qt) break;
        if (kt < qt) LOADKV(kA0, kA1, vA0, vA1, kt + 1);
        TILE_COMPUTE(kB0, kB1, vB0, vB1, kt == qt);
        if (++kt > qt) break;
    }

    const float inv = c_p / lrun;
    float* lt = lds_t[w];
    #pragma unroll
    for (int r = 0; r < 16; ++r) {
        const int d = (r & 3) + 8 * (r >> 2) + 4 * hi;
        lt[l31 * 33 + d] = ot[r] * inv;
    }
    __syncthreads();
    const int q0w = qt * 32;
    #pragma unroll
    for (int rr = 0; rr < 4; ++rr) {
        const int ql = rr * 8 + (lane >> 3);
        const int d0 = (lane & 7) * 4;
        const float* lp = &lt[ql * 33 + d0];
        float* op = out + ((size_t)b * S + q0w + ql) * D + h * 32 + d0;
        float4 cur = *(const float4*)op;
        cur.x += lp[0]; cur.y += lp[1]; cur.z += lp[2]; cur.w += lp[3];
        *(float4*)op = cur;
    }
}

// ---------------------------------------------------------------------------
extern "C" void kernel_launch(void* const* d_in, const int* in_sizes, int n_in,
                              void* d_out, int out_size, void* d_ws, size_t ws_size,
                              hipStream_t stream)
{
    (void)in_sizes; (void)n_in; (void)out_size; (void)ws_size;
    const float* query = (const float*)d_in[0];
    const float* key_  = (const float*)d_in[1];
    const float* value = (const float*)d_in[2];
    const float* rel   = (const float*)d_in[3];
    const float* tsp   = (const float*)d_in[4];
    const float* l1p   = (const float*)d_in[5];
    const float* l2p   = (const float*)d_in[6];
    const float* Wq    = (const float*)d_in[7];
    const float* bq    = (const float*)d_in[8];
    const float* Wk    = (const float*)d_in[9];
    const float* bk    = (const float*)d_in[10];
    const float* Wv    = (const float*)d_in[11];
    const float* bv    = (const float*)d_in[12];
    float* out = (float*)d_out;

    // ws: qb [4MB] | kb [4MB] | vtb [4MB] | csum [8KB]
    ushort* qbuf  = (ushort*)d_ws;
    ushort* kbuf  = (ushort*)((char*)d_ws + (4u  << 20));
    ushort* vtbuf = (ushort*)((char*)d_ws + (8u  << 20));
    float*  csum  = (float*)((char*)d_ws + (12u << 20));

    const float qscale = 1.4426950408889634f * 0.17677669529663687f; // log2e/sqrt(32)

    zero_csum<<<8, 256, 0, stream>>>(csum);

    proj_mfma<<<dim3(128, 3), 512, 0, stream>>>(
        query, key_, value, Wq, Wk, Wv, bq, bk, bv, qscale,
        qbuf, kbuf, vtbuf, csum);

    timerel_mfma<<<dim3(S / 32, B), 512, 0, stream>>>(
        tsp, rel, vtbuf, csum, l1p, l2p, out);

    flash_mfma<<<512, 256, 0, stream>>>(qbuf, kbuf, vtbuf, l1p, l2p, out);
}